// Round 1
// 1797.907 us; speedup vs baseline: 1.4416x; 1.4416x over previous
//
#include <hip/hip_runtime.h>
#include <math.h>

#define S_    2048
#define B_    4
#define E_    1024
#define F_    4096
#define H_    16
#define NE_   8
#define CAP_  2048
#define T_    (S_*B_)     // 8192 tokens
#define HALF_ (E_/2)      // 512

typedef unsigned short u16;
typedef unsigned long long u64;
typedef __attribute__((ext_vector_type(8))) short bf16x8;
typedef __attribute__((ext_vector_type(4))) float f32x4;

__device__ __forceinline__ float bf2f(u16 u) {
  union { unsigned int i; float f; } v; v.i = ((unsigned int)u) << 16; return v.f;
}
__device__ __forceinline__ u16 f2bf(float f) {
  union { float f; unsigned int i; } v; v.f = f;
  unsigned int x = v.i;
  return (u16)((x + 0x7fffu + ((x >> 16) & 1u)) >> 16);
}
__device__ __forceinline__ void splitf(float v, u16& hi, u16& lo) {
  hi = f2bf(v);
  lo = f2bf(v - bf2f(hi));
}
__device__ __forceinline__ f32x4 mfma16(bf16x8 a, bf16x8 b, f32x4 c) {
  return __builtin_amdgcn_mfma_f32_16x16x32_bf16(a, b, c, 0, 0, 0);
}
// async global->LDS, 16B per lane. Global addr is per-lane; LDS dest must be
// wave-uniform base + lane*16 (our staging index IS linear: offset = tid*16).
__device__ __forceinline__ void glds16(const u16* g, u16* l) {
  __builtin_amdgcn_global_load_lds(
      (const __attribute__((address_space(1))) void*)g,
      (__attribute__((address_space(3))) void*)l, 16, 0, 0);
}

// ---------------- trig tables (fp64) ----------------
__global__ __launch_bounds__(256) void trig_kernel(float* __restrict__ cosT,
                                                   float* __restrict__ sinT) {
  int s = blockIdx.x;
  for (int j = threadIdx.x; j < HALF_; j += 256) {
    double inv = pow(10000.0, -(double)j / (double)HALF_);
    double fr = (double)s * inv;
    cosT[(size_t)s*HALF_ + j] = (float)cos(fr);
    sinT[(size_t)s*HALF_ + j] = (float)sin(fr);
  }
}

// ---------------- split fp32 -> bf16 hi/lo ----------------
__global__ __launch_bounds__(256) void split_kernel(const float* __restrict__ src,
                                                    u16* __restrict__ hi, u16* __restrict__ lo, int n) {
  int i = blockIdx.x*256 + threadIdx.x;
  if (i < n) {
    float v = src[i];
    u16 h, l; splitf(v, h, l);
    hi[i] = h; lo[i] = l;
  }
}

// ---------------- transpose + convert: src fp32 [Z][R][C] -> dst bf16 [Z][C][R] ----------------
__global__ __launch_bounds__(256) void transp_bf16_kernel(const float* __restrict__ src,
                                                          u16* __restrict__ dst, int R, int C) {
  int z = blockIdx.z;
  src += (size_t)z*R*C; dst += (size_t)z*R*C;
  __shared__ float tile[32][33];
  int r0 = blockIdx.y*32, c0 = blockIdx.x*32;
  int tr = threadIdx.x >> 5, tc = threadIdx.x & 31;
  for (int i = 0; i < 4; i++)
    tile[tr + i*8][tc] = src[(size_t)(r0 + tr + i*8)*C + c0 + tc];
  __syncthreads();
  for (int i = 0; i < 4; i++)
    dst[(size_t)(c0 + tr + i*8)*R + r0 + tc] = f2bf(tile[tc][tr + i*8]);
}

// ---------------- LayerNorm + RoPE -> bf16 hi/lo ----------------
__global__ __launch_bounds__(256) void ln_rope_kernel(
    const float* __restrict__ in, const float* __restrict__ sw, const float* __restrict__ bw,
    const float* __restrict__ cosT, const float* __restrict__ sinT,
    u16* __restrict__ outh, u16* __restrict__ outl) {
  __shared__ float xb[E_];
  __shared__ double red[256];
  __shared__ double stats[2];
  int t = blockIdx.x;
  int s = t / B_;
  const float* row = in + (size_t)t * E_;
  int tid = threadIdx.x;
  double sum = 0.0;
  for (int k = 0; k < 4; k++) {
    int e = tid + k*256;
    float f = row[e];
    xb[e] = f;
    sum += (double)f;
  }
  red[tid] = sum; __syncthreads();
  for (int off = 128; off > 0; off >>= 1) {
    if (tid < off) red[tid] += red[tid+off];
    __syncthreads();
  }
  if (tid == 0) stats[0] = red[0] / (double)E_;
  __syncthreads();
  double m = stats[0];
  double sq = 0.0;
  for (int k = 0; k < 4; k++) {
    int e = tid + k*256;
    double d = (double)xb[e] - m;
    sq += d*d;
  }
  red[tid] = sq; __syncthreads();
  for (int off = 128; off > 0; off >>= 1) {
    if (tid < off) red[tid] += red[tid+off];
    __syncthreads();
  }
  if (tid == 0) stats[1] = 1.0 / sqrt(red[0] / (double)E_ + 1e-5);
  __syncthreads();
  float mf = (float)m, rs = (float)stats[1];
  for (int k = 0; k < 2; k++) {
    int j = tid + k*256;    // 0..511
    float n1 = (xb[j]        - mf)*rs*sw[j]        + bw[j];
    float n2 = (xb[j+HALF_]  - mf)*rs*sw[j+HALF_]  + bw[j+HALF_];
    float c  = cosT[(size_t)s*HALF_ + j];
    float sn = sinT[(size_t)s*HALF_ + j];
    float o1 = n1*c - n2*sn;
    float o2 = n1*sn + n2*c;
    u16 h, l;
    splitf(o1, h, l);
    outh[(size_t)t*E_ + j] = h; outl[(size_t)t*E_ + j] = l;
    splitf(o2, h, l);
    outh[(size_t)t*E_ + HALF_ + j] = h; outl[(size_t)t*E_ + HALF_ + j] = l;
  }
}

// ---------------- LayerNorm (no rope) -> fp32 xn + bf16 xnb ----------------
__global__ __launch_bounds__(256) void ln2_kernel(
    const float* __restrict__ in, const float* __restrict__ sw, const float* __restrict__ bw,
    float* __restrict__ out, u16* __restrict__ outb) {
  __shared__ float xb[E_];
  __shared__ double red[256];
  __shared__ double stats[2];
  int t = blockIdx.x;
  const float* row = in + (size_t)t * E_;
  int tid = threadIdx.x;
  double sum = 0.0;
  for (int k = 0; k < 4; k++) {
    int e = tid + k*256;
    float f = row[e];
    xb[e] = f;
    sum += (double)f;
  }
  red[tid] = sum; __syncthreads();
  for (int off = 128; off > 0; off >>= 1) {
    if (tid < off) red[tid] += red[tid+off];
    __syncthreads();
  }
  if (tid == 0) stats[0] = red[0] / (double)E_;
  __syncthreads();
  double m = stats[0];
  double sq = 0.0;
  for (int k = 0; k < 4; k++) {
    int e = tid + k*256;
    double d = (double)xb[e] - m;
    sq += d*d;
  }
  red[tid] = sq; __syncthreads();
  for (int off = 128; off > 0; off >>= 1) {
    if (tid < off) red[tid] += red[tid+off];
    __syncthreads();
  }
  if (tid == 0) stats[1] = 1.0 / sqrt(red[0] / (double)E_ + 1e-5);
  __syncthreads();
  float mf = (float)m, rs = (float)stats[1];
  for (int k = 0; k < 4; k++) {
    int e = tid + k*256;
    float v = (xb[e] - mf)*rs*sw[e] + bw[e];
    out[(size_t)t*E_ + e] = v;
    outb[(size_t)t*E_ + e] = f2bf(v);
  }
}

// ---------------- MFMA GEMM: C = A[M][K] * B[N][K]^T ----------------
// MODE 0: split-3x, +bias, store bf16 hi/lo (QKV, z=0..2 selects slice)
// MODE 1: split-3x, +bias +res, store fp32 (out-proj)
template<int MODE>
__global__ __launch_bounds__(256) void gemm_mfma(
    const u16* __restrict__ Ah, const u16* __restrict__ Al,
    const u16* __restrict__ Bh, const u16* __restrict__ Bl,
    const float* __restrict__ bias, const float* __restrict__ res,
    float* __restrict__ Cf, u16* __restrict__ Ch, u16* __restrict__ Cl,
    int M, int N, int K) {
  __shared__ u16 Ash[128][40];
  __shared__ u16 Bsh[128][40];
  __shared__ u16 Asl[128][40];
  __shared__ u16 Bsl[128][40];
  int tid = threadIdx.x;
  int m0 = blockIdx.y*128, n0 = blockIdx.x*128;
  if constexpr (MODE == 0) {
    int z = blockIdx.z;
    Ah += (size_t)z*M*K;  Al += (size_t)z*M*K;
    Bh += (size_t)z*N*K;  Bl += (size_t)z*N*K;
    bias += (size_t)z*N;
    Ch += (size_t)z*M*N;  Cl += (size_t)z*M*N;
  }
  int wave = tid>>6, lane = tid&63, quad = lane>>4, l16 = lane&15;
  int wm = (wave>>1)*64, wn = (wave&1)*64;
  f32x4 acc[4][4];
  for (int i = 0; i < 4; i++)
    for (int j = 0; j < 4; j++)
      acc[i][j] = f32x4{0.f, 0.f, 0.f, 0.f};
  for (int k0 = 0; k0 < K; k0 += 32) {
    for (int c = tid; c < 512; c += 256) {
      int r = c >> 2, k8 = (c & 3) * 8;
      *(int4*)&Ash[r][k8] = *(const int4*)(Ah + (size_t)(m0+r)*K + k0 + k8);
      *(int4*)&Asl[r][k8] = *(const int4*)(Al + (size_t)(m0+r)*K + k0 + k8);
      *(int4*)&Bsh[r][k8] = *(const int4*)(Bh + (size_t)(n0+r)*K + k0 + k8);
      *(int4*)&Bsl[r][k8] = *(const int4*)(Bl + (size_t)(n0+r)*K + k0 + k8);
    }
    __syncthreads();
    bf16x8 af[4], bf[4];
    bf16x8 afl[4], bfl[4];
#pragma unroll
    for (int t4 = 0; t4 < 4; t4++) {
      af[t4] = *(const bf16x8*)&Ash[wm + t4*16 + l16][quad*8];
      bf[t4] = *(const bf16x8*)&Bsh[wn + t4*16 + l16][quad*8];
      afl[t4] = *(const bf16x8*)&Asl[wm + t4*16 + l16][quad*8];
      bfl[t4] = *(const bf16x8*)&Bsl[wn + t4*16 + l16][quad*8];
    }
#pragma unroll
    for (int i = 0; i < 4; i++)
#pragma unroll
      for (int j = 0; j < 4; j++) {
        f32x4 a = acc[i][j];
        a = mfma16(af[i],  bf[j],  a);
        a = mfma16(af[i],  bfl[j], a);
        a = mfma16(afl[i], bf[j],  a);
        acc[i][j] = a;
      }
    __syncthreads();
  }
  for (int i = 0; i < 4; i++) {
    for (int j = 0; j < 4; j++) {
      for (int r = 0; r < 4; r++) {
        int rl  = wm + i*16 + quad*4 + r;
        int col = n0 + wn + j*16 + l16;
        float v = acc[i][j][r];
        if constexpr (MODE == 0) {
          v += bias[col];
          u16 hi, lo; splitf(v, hi, lo);
          size_t o = (size_t)(m0+rl)*N + col;
          Ch[o] = hi; Cl[o] = lo;
        } else {
          size_t o = (size_t)(m0+rl)*N + col;
          Cf[o] = v + bias[col] + res[o];
        }
      }
    }
  }
}

// ---------------- gathered expert-FFN GEMM, 2-phase gl_lds pipeline ----------------
// C[tok] = gelu(A[tok] * B^T)        (MODE 2, bf16 out)
// C[tok] = A[tok] * B^T + res[tok]   (MODE 3, fp32 out)
// LDS tiles are unpadded [128][32] u16 (64B rows) so global_load_lds dest is
// linear lane*16; bank conflicts handled by chunk-XOR swizzle applied BOTH at
// the (per-lane) global source address and at the ds_read_b128 fragment reads.
template<int MODE>
__global__ __launch_bounds__(256) void gemm_gather(
    const u16* __restrict__ A, const u16* __restrict__ B,
    const float* __restrict__ res,
    float* __restrict__ Cf, u16* __restrict__ Ch,
    int N, int K,
    const int* __restrict__ elist, const int* __restrict__ ecount) {
  __shared__ u16 As[2][128][32];
  __shared__ u16 Bs[2][128][32];
  __shared__ int toks[128];
  int tid = threadIdx.x;
  int m0 = blockIdx.y*128, n0 = blockIdx.x*128;
  int e = blockIdx.z;
  int cnt = ecount[e];
  if (m0 >= cnt) return;
  B += (size_t)e*N*K;
  const int* el = elist + e*CAP_;
  if (tid < 128) {
    int r = m0 + tid;
    toks[tid] = (r < cnt) ? el[r] : -1;
  }
  __syncthreads();
  // staging: chunk-entry c in [0,512): row r=c>>2, chunk ch=c&3 (16B each);
  // thread handles c=tid and c=tid+256 -> LDS offsets tid*16, (tid+256)*16 (linear)
  int r0 = tid >> 2, ch0 = tid & 3;
  int r1 = r0 + 64;                      // (tid+256)>>2 ; r1&3 == r0&3
  int s8 = (ch0 ^ (r0 & 3)) * 8;         // swizzled source chunk (u16 elems)
  int tokA0 = toks[r0], tokA1 = toks[r1];
  const u16* gA0 = A + (size_t)(tokA0 >= 0 ? tokA0 : 0)*K + s8;
  const u16* gA1 = A + (size_t)(tokA1 >= 0 ? tokA1 : 0)*K + s8;
  const u16* gB0 = B + (size_t)(n0 + r0)*K + s8;
  const u16* gB1 = B + (size_t)(n0 + r1)*K + s8;
  u16* dA0 = &As[0][r0][ch0*8];          // buffer stride = 4096 u16
  u16* dA1 = &As[0][r1][ch0*8];
  u16* dB0 = &Bs[0][r0][ch0*8];
  u16* dB1 = &Bs[0][r1][ch0*8];
  int wave = tid>>6, lane = tid&63, quad = lane>>4, l16 = lane&15;
  int wm = (wave>>1)*64, wn = (wave&1)*64;
  int chA = (quad ^ (l16 & 3)) * 8;      // swizzled read chunk for frag loads
  f32x4 acc[4][4];
  for (int i = 0; i < 4; i++)
    for (int j = 0; j < 4; j++)
      acc[i][j] = f32x4{0.f, 0.f, 0.f, 0.f};
  // prologue: stage tile 0
  glds16(gA0, dA0); glds16(gA1, dA1);
  glds16(gB0, dB0); glds16(gB1, dB1);
  asm volatile("s_waitcnt vmcnt(0)" ::: "memory");
  __builtin_amdgcn_s_barrier();
  int cur = 0;
  for (int k0 = 0; k0 < K; k0 += 32) {
    int nxt = cur ^ 1;
    if (k0 + 32 < K) {
      int ko = k0 + 32;
      glds16(gA0 + ko, dA0 + nxt*4096); glds16(gA1 + ko, dA1 + nxt*4096);
      glds16(gB0 + ko, dB0 + nxt*4096); glds16(gB1 + ko, dB1 + nxt*4096);
    }
    const u16* aS = &As[cur][0][0];
    const u16* bS = &Bs[cur][0][0];
    bf16x8 af[4], bfr[4];
#pragma unroll
    for (int t4 = 0; t4 < 4; t4++) {
      af[t4]  = *(const bf16x8*)(aS + (wm + t4*16 + l16)*32 + chA);
      bfr[t4] = *(const bf16x8*)(bS + (wn + t4*16 + l16)*32 + chA);
    }
#pragma unroll
    for (int i = 0; i < 4; i++)
#pragma unroll
      for (int j = 0; j < 4; j++)
        acc[i][j] = mfma16(af[i], bfr[j], acc[i][j]);
    asm volatile("s_waitcnt vmcnt(0)" ::: "memory");
    __builtin_amdgcn_s_barrier();
    cur = nxt;
  }
  for (int i = 0; i < 4; i++) {
    for (int j = 0; j < 4; j++) {
      for (int r = 0; r < 4; r++) {
        int rl  = wm + i*16 + quad*4 + r;
        int col = n0 + wn + j*16 + l16;
        float v = acc[i][j][r];
        int tok = toks[rl];
        if (tok >= 0) {
          if constexpr (MODE == 2) {
            float g = 0.5f*v*(1.0f + erff(v*0.70710678118654752f));
            Ch[(size_t)tok*N + col] = f2bf(g);
          } else {
            size_t o = (size_t)tok*N + col;
            Cf[o] = v + res[o];
          }
        }
      }
    }
  }
}

// ---------------- flash attention, split-bf16 MFMA, TQ=64 / TK=64 ----------------
__global__ __launch_bounds__(256) void attn_mfma_kernel(
    const u16* __restrict__ qh_, const u16* __restrict__ ql_,
    const u16* __restrict__ kh_, const u16* __restrict__ kl_,
    const u16* __restrict__ vh_, const u16* __restrict__ vl_,
    u16* __restrict__ ch_, u16* __restrict__ cl_) {
  __shared__ u16 Kh[64][72], Kl[64][72];
  __shared__ u16 Vth[64][72], Vtl[64][72];   // transposed: [d][k]
  __shared__ u16 Ph[64][72], Pl[64][72];     // [q][k]
  int bh = blockIdx.y;
  int b = bh >> 4, hh = bh & 15;
  int q0 = blockIdx.x * 64;
  int tid = threadIdx.x, wave = tid>>6, lane = tid&63, quad = lane>>4, l16 = lane&15;
  bf16x8 qfh[2], qfl[2];
  {
    int qrow = q0 + wave*16 + l16;
    size_t base = ((size_t)qrow*B_ + b)*E_ + hh*64;
    for (int st = 0; st < 2; st++) {
      qfh[st] = *(const bf16x8*)(qh_ + base + st*32 + quad*8);
      qfl[st] = *(const bf16x8*)(ql_ + base + st*32 + quad*8);
    }
  }
  float m_i[4], l_i[4];
  f32x4 acc[4];
  for (int r = 0; r < 4; r++) { m_i[r] = -INFINITY; l_i[r] = 0.f; }
  for (int d = 0; d < 4; d++) acc[d] = f32x4{0.f,0.f,0.f,0.f};
  for (int kt = 0; kt < S_/64; kt++) {
    __syncthreads();
    for (int c = tid; c < 512; c += 256) {
      int r = c >> 3, k8 = (c & 7) * 8;
      size_t gb = ((size_t)(kt*64 + r)*B_ + b)*E_ + hh*64 + k8;
      *(int4*)&Kh[r][k8] = *(const int4*)(kh_ + gb);
      *(int4*)&Kl[r][k8] = *(const int4*)(kl_ + gb);
      u16 tmp[8];
      *(int4*)tmp = *(const int4*)(vh_ + gb);
#pragma unroll
      for (int i = 0; i < 8; i++) Vth[k8+i][r] = tmp[i];
      *(int4*)tmp = *(const int4*)(vl_ + gb);
#pragma unroll
      for (int i = 0; i < 8; i++) Vtl[k8+i][r] = tmp[i];
    }
    __syncthreads();
    f32x4 sc[4];
#pragma unroll
    for (int ct = 0; ct < 4; ct++) {
      f32x4 s = f32x4{0.f,0.f,0.f,0.f};
#pragma unroll
      for (int st = 0; st < 2; st++) {
        bf16x8 kh = *(const bf16x8*)&Kh[ct*16 + l16][st*32 + quad*8];
        bf16x8 kl = *(const bf16x8*)&Kl[ct*16 + l16][st*32 + quad*8];
        s = mfma16(qfh[st], kh, s);
        s = mfma16(qfh[st], kl, s);
        s = mfma16(qfl[st], kh, s);
      }
      sc[ct] = s;
    }
#pragma unroll
    for (int ct = 0; ct < 4; ct++)
#pragma unroll
      for (int r = 0; r < 4; r++)
        sc[ct][r] *= 0.125f;
    float mx[4], alpha[4], rs[4];
#pragma unroll
    for (int r = 0; r < 4; r++)
      mx[r] = fmaxf(fmaxf(sc[0][r], sc[1][r]), fmaxf(sc[2][r], sc[3][r]));
#pragma unroll
    for (int off = 1; off < 16; off <<= 1)
#pragma unroll
      for (int r = 0; r < 4; r++)
        mx[r] = fmaxf(mx[r], __shfl_xor(mx[r], off, 64));
#pragma unroll
    for (int r = 0; r < 4; r++) {
      float mn = fmaxf(m_i[r], mx[r]);
      alpha[r] = expf(m_i[r] - mn);
      m_i[r] = mn;
      rs[r] = 0.f;
    }
#pragma unroll
    for (int ct = 0; ct < 4; ct++)
#pragma unroll
      for (int r = 0; r < 4; r++) {
        float p = expf(sc[ct][r] - m_i[r]);
        sc[ct][r] = p;
        rs[r] += p;
      }
#pragma unroll
    for (int off = 1; off < 16; off <<= 1)
#pragma unroll
      for (int r = 0; r < 4; r++)
        rs[r] += __shfl_xor(rs[r], off, 64);
#pragma unroll
    for (int r = 0; r < 4; r++)
      l_i[r] = l_i[r]*alpha[r] + rs[r];
#pragma unroll
    for (int ct = 0; ct < 4; ct++)
#pragma unroll
      for (int r = 0; r < 4; r++) {
        u16 hi, lo; splitf(sc[ct][r], hi, lo);
        int q = wave*16 + quad*4 + r;
        int k = ct*16 + l16;
        Ph[q][k] = hi; Pl[q][k] = lo;
      }
#pragma unroll
    for (int d = 0; d < 4; d++)
#pragma unroll
      for (int r = 0; r < 4; r++)
        acc[d][r] *= alpha[r];
    __syncthreads();
#pragma unroll
    for (int dt = 0; dt < 4; dt++) {
      f32x4 a = acc[dt];
#pragma unroll
      for (int st = 0; st < 2; st++) {
        bf16x8 ph = *(const bf16x8*)&Ph[wave*16 + l16][st*32 + quad*8];
        bf16x8 pl = *(const bf16x8*)&Pl[wave*16 + l16][st*32 + quad*8];
        bf16x8 vh = *(const bf16x8*)&Vth[dt*16 + l16][st*32 + quad*8];
        bf16x8 vl = *(const bf16x8*)&Vtl[dt*16 + l16][st*32 + quad*8];
        a = mfma16(ph, vh, a);
        a = mfma16(ph, vl, a);
        a = mfma16(pl, vh, a);
      }
      acc[dt] = a;
    }
  }
  for (int dt = 0; dt < 4; dt++) {
    for (int r = 0; r < 4; r++) {
      float v = acc[dt][r] / l_i[r];
      int q = q0 + wave*16 + quad*4 + r;
      size_t o = ((size_t)q*B_ + b)*E_ + hh*64 + dt*16 + l16;
      u16 hi, lo; splitf(v, hi, lo);
      ch_[o] = hi; cl_[o] = lo;
    }
  }
}

// ---------------- router: logits (fp64 accum) + argmax ----------------
__global__ __launch_bounds__(256) void router_kernel(
    const float* __restrict__ xn, const float* __restrict__ rw, int* __restrict__ top) {
  __shared__ float lg[32][9];
  int t0 = blockIdx.x * 32;
  int tl = threadIdx.x >> 3;
  int n = threadIdx.x & 7;
  int t = t0 + tl;
  const float* xr = xn + (size_t)t * E_;
  double acc = 0.0;
  for (int e = 0; e < E_; e++) acc += (double)xr[e] * (double)rw[e*NE_ + n];
  lg[tl][n] = (float)acc;
  __syncthreads();
  if (n == 0) {
    float best = lg[tl][0]; int bi = 0;
    for (int i = 1; i < 8; i++) {
      float v = lg[tl][i];
      if (v > best) { best = v; bi = i; }
    }
    top[t] = bi;
  }
}

// ---------------- capacity (Switch cumsum) ----------------
__global__ __launch_bounds__(256) void capacity_kernel(
    const int* __restrict__ top, int* __restrict__ elist, int* __restrict__ ecount) {
  __shared__ int tl[T_];
  __shared__ int cnts[256][NE_];
  int tid = threadIdx.x;
  for (int i = tid; i < T_; i += 256) tl[i] = top[i];
  __syncthreads();
  int c[NE_] = {};
  int base = tid * 32;
  for (int i = 0; i < 32; i++) c[tl[base+i]]++;
  for (int n = 0; n < NE_; n++) cnts[tid][n] = c[n];
  __syncthreads();
  if (tid < NE_) {
    int run = 0;
    for (int i = 0; i < 256; i++) {
      int v = cnts[i][tid];
      cnts[i][tid] = run;
      run += v;
    }
    ecount[tid] = min(run, CAP_);
  }
  __syncthreads();
  int pos[NE_];
  for (int n = 0; n < NE_; n++) pos[n] = cnts[tid][n];
  for (int i = 0; i < 32; i++) {
    int t = base + i;
    int e = tl[t];
    int p = pos[e]++;
    if (p < CAP_) elist[e*CAP_ + p] = t;
  }
}

// ---------------- out = x (dropped tokens keep residual) ----------------
__global__ __launch_bounds__(256) void fill_out_kernel(
    const float* __restrict__ x, float* __restrict__ out) {
  size_t i4 = ((size_t)blockIdx.x*256 + threadIdx.x) * 4;
  *(float4*)(out + i4) = *(const float4*)(x + i4);
}

extern "C" void kernel_launch(void* const* d_in, const int* in_sizes, int n_in,
                              void* d_out, int out_size, void* d_ws, size_t ws_size,
                              hipStream_t stream) {
  (void)in_sizes; (void)n_in; (void)out_size; (void)ws_size;
  const float* query      = (const float*)d_in[0];
  const float* key        = (const float*)d_in[1];
  const float* value      = (const float*)d_in[2];
  const float* in_proj_w  = (const float*)d_in[3];
  const float* in_proj_b  = (const float*)d_in[4];
  const float* out_proj_w = (const float*)d_in[5];
  const float* out_proj_b = (const float*)d_in[6];
  const float* norm1_s    = (const float*)d_in[7];
  const float* norm1_b    = (const float*)d_in[8];
  const float* norm2_s    = (const float*)d_in[9];
  const float* norm2_b    = (const float*)d_in[10];
  const float* router_w   = (const float*)d_in[11];
  const float* wi         = (const float*)d_in[12];
  const float* wo         = (const float*)d_in[13];
  float* out = (float*)d_out;

  char* wsb = (char*)d_ws;
  const size_t TE = (size_t)T_ * E_;          // 8,388,608
  // R1 @0 (134,217,728 B): LN outputs hi/lo [3][T][E]; later wit+wot
  u16* nh  = (u16*)(wsb + 0);                 // 3*TE shorts
  u16* nl  = nh + 3*TE;
  u16* wit = (u16*)(wsb + 0);                 // [8][F][E] bf16
  u16* wot = wit + (size_t)8*F_*E_;
  // R2 @134,217,728 (100,663,296 B): QKV proj hi/lo [3][T][E]; later h + xnb
  u16* pph  = (u16*)(wsb + 134217728ULL);
  u16* ppl  = pph + 3*TE;
  u16* hbuf = (u16*)(wsb + 134217728ULL);     // [T][F] bf16
  u16* xnb  = hbuf + (size_t)T_*F_;
  // R3 @234,881,024 (33,554,432 B): ctx hi/lo; later xn fp32
  u16* ctxh = (u16*)(wsb + 234881024ULL);
  u16* ctxl = ctxh + TE;
  float* xn = (float*)(wsb + 234881024ULL);
  // R4: x fp32
  float* x  = (float*)(wsb + 268435456ULL);
  // R5: trig
  float* cosT = (float*)(wsb + 301989888ULL);
  float* sinT = cosT + (size_t)S_*HALF_;
  // R6: proj weight splits
  u16* iph = (u16*)(wsb + 310378496ULL);
  u16* ipl = iph + (size_t)3*E_*E_;
  u16* oph = ipl + (size_t)3*E_*E_;
  u16* opl = oph + (size_t)E_*E_;
  // R7: routing
  int* top    = (int*)(wsb + 327155712ULL);
  int* elist  = top + T_;
  int* ecount = elist + NE_*CAP_;

  trig_kernel<<<dim3(S_), dim3(256), 0, stream>>>(cosT, sinT);
  split_kernel<<<dim3((3*E_*E_)/256), dim3(256), 0, stream>>>(in_proj_w, iph, ipl, 3*E_*E_);
  split_kernel<<<dim3((E_*E_)/256), dim3(256), 0, stream>>>(out_proj_w, oph, opl, E_*E_);
  ln_rope_kernel<<<dim3(T_), dim3(256), 0, stream>>>(query, norm1_s, norm1_b, cosT, sinT, nh,        nl);
  ln_rope_kernel<<<dim3(T_), dim3(256), 0, stream>>>(key,   norm1_s, norm1_b, cosT, sinT, nh + TE,   nl + TE);
  ln_rope_kernel<<<dim3(T_), dim3(256), 0, stream>>>(value, norm1_s, norm1_b, cosT, sinT, nh + 2*TE, nl + 2*TE);
  // QKV projections (split-3x): z selects (qn,kn,vn) x in_proj slice -> pph/ppl
  gemm_mfma<0><<<dim3(E_/128, T_/128, 3), dim3(256), 0, stream>>>(
      nh, nl, iph, ipl, in_proj_b, nullptr, nullptr, pph, ppl,
      T_, E_, E_);
  // wi/wo transpose+convert (R1 now free)
  transp_bf16_kernel<<<dim3(F_/32, E_/32, 8), dim3(256), 0, stream>>>(wi, wit, E_, F_);
  transp_bf16_kernel<<<dim3(E_/32, F_/32, 8), dim3(256), 0, stream>>>(wo, wot, F_, E_);
  attn_mfma_kernel<<<dim3(S_/64, B_*H_), dim3(256), 0, stream>>>(
      pph, ppl, pph + TE, ppl + TE, pph + 2*TE, ppl + 2*TE, ctxh, ctxl);
  // out-proj (split-3x) + bias + residual(query) -> x fp32
  gemm_mfma<1><<<dim3(E_/128, T_/128, 1), dim3(256), 0, stream>>>(
      ctxh, ctxl, oph, opl, out_proj_b, query, x, nullptr, nullptr,
      T_, E_, E_);
  ln2_kernel<<<dim3(T_), dim3(256), 0, stream>>>(x, norm2_s, norm2_b, xn, xnb);
  router_kernel<<<dim3(T_/32), dim3(256), 0, stream>>>(xn, router_w, top);
  capacity_kernel<<<dim3(1), dim3(256), 0, stream>>>(top, elist, ecount);
  fill_out_kernel<<<dim3(TE/1024), dim3(256), 0, stream>>>(x, out);
  // expert FFN (plain bf16 MFMA, gathered, 2-phase gl_lds pipeline)
  gemm_gather<2><<<dim3(F_/128, CAP_/128, NE_), dim3(256), 0, stream>>>(
      xnb, wit, nullptr, nullptr, hbuf, F_, E_, elist, ecount);
  gemm_gather<3><<<dim3(E_/128, CAP_/128, NE_), dim3(256), 0, stream>>>(
      hbuf, wot, x, out, nullptr, E_, F_, elist, ecount);
}

// Round 2
// 1594.933 us; speedup vs baseline: 1.6251x; 1.1273x over previous
//
#include <hip/hip_runtime.h>
#include <math.h>

#define S_    2048
#define B_    4
#define E_    1024
#define F_    4096
#define H_    16
#define NE_   8
#define CAP_  2048
#define T_    (S_*B_)     // 8192 tokens
#define HALF_ (E_/2)      // 512

typedef unsigned short u16;
typedef unsigned long long u64;
typedef __attribute__((ext_vector_type(8))) short bf16x8;
typedef __attribute__((ext_vector_type(4))) float f32x4;

__device__ __forceinline__ float bf2f(u16 u) {
  union { unsigned int i; float f; } v; v.i = ((unsigned int)u) << 16; return v.f;
}
__device__ __forceinline__ u16 f2bf(float f) {
  union { float f; unsigned int i; } v; v.f = f;
  unsigned int x = v.i;
  return (u16)((x + 0x7fffu + ((x >> 16) & 1u)) >> 16);
}
__device__ __forceinline__ void splitf(float v, u16& hi, u16& lo) {
  hi = f2bf(v);
  lo = f2bf(v - bf2f(hi));
}
__device__ __forceinline__ f32x4 mfma16(bf16x8 a, bf16x8 b, f32x4 c) {
  return __builtin_amdgcn_mfma_f32_16x16x32_bf16(a, b, c, 0, 0, 0);
}
// async global->LDS, 16B per lane. Global addr is per-lane; LDS dest must be
// wave-uniform base + lane*16 (our staging index IS linear: offset = tid*16).
__device__ __forceinline__ void glds16(const u16* g, u16* l) {
  __builtin_amdgcn_global_load_lds(
      (const __attribute__((address_space(1))) void*)g,
      (__attribute__((address_space(3))) void*)l, 16, 0, 0);
}

// ---------------- trig tables (fp64) ----------------
__global__ __launch_bounds__(256) void trig_kernel(float* __restrict__ cosT,
                                                   float* __restrict__ sinT) {
  int s = blockIdx.x;
  for (int j = threadIdx.x; j < HALF_; j += 256) {
    double inv = pow(10000.0, -(double)j / (double)HALF_);
    double fr = (double)s * inv;
    cosT[(size_t)s*HALF_ + j] = (float)cos(fr);
    sinT[(size_t)s*HALF_ + j] = (float)sin(fr);
  }
}

// ---------------- split fp32 -> bf16 hi/lo ----------------
__global__ __launch_bounds__(256) void split_kernel(const float* __restrict__ src,
                                                    u16* __restrict__ hi, u16* __restrict__ lo, int n) {
  int i = blockIdx.x*256 + threadIdx.x;
  if (i < n) {
    float v = src[i];
    u16 h, l; splitf(v, h, l);
    hi[i] = h; lo[i] = l;
  }
}

// ---------------- transpose + convert: src fp32 [Z][R][C] -> dst bf16 [Z][C][R] ----------------
__global__ __launch_bounds__(256) void transp_bf16_kernel(const float* __restrict__ src,
                                                          u16* __restrict__ dst, int R, int C) {
  int z = blockIdx.z;
  src += (size_t)z*R*C; dst += (size_t)z*R*C;
  __shared__ float tile[32][33];
  int r0 = blockIdx.y*32, c0 = blockIdx.x*32;
  int tr = threadIdx.x >> 5, tc = threadIdx.x & 31;
  for (int i = 0; i < 4; i++)
    tile[tr + i*8][tc] = src[(size_t)(r0 + tr + i*8)*C + c0 + tc];
  __syncthreads();
  for (int i = 0; i < 4; i++)
    dst[(size_t)(c0 + tr + i*8)*R + r0 + tc] = f2bf(tile[tc][tr + i*8]);
}

// ---------------- V transpose: [s][b][h*64+d] u16 -> [b*H+h][d][s] u16 (hi & lo) ----------------
__global__ __launch_bounds__(256) void vtransp_kernel(
    const u16* __restrict__ vh, const u16* __restrict__ vl,
    u16* __restrict__ dh, u16* __restrict__ dl) {
  __shared__ u16 tile[32][34];
  int s0 = blockIdx.x * 32;
  int d0 = blockIdx.y * 32;
  int bh = blockIdx.z;
  int b = bh >> 4, h = bh & 15;
  int tr = threadIdx.x >> 5, tc = threadIdx.x & 31;
#pragma unroll
  for (int comp = 0; comp < 2; comp++) {
    const u16* src = comp ? vl : vh;
    u16* dst = comp ? dl : dh;
    for (int i = 0; i < 4; i++)
      tile[tr + i*8][tc] = src[((size_t)(s0 + tr + i*8)*B_ + b)*E_ + h*64 + d0 + tc];
    __syncthreads();
    for (int i = 0; i < 4; i++)
      dst[((size_t)bh*64 + d0 + tr + i*8)*S_ + s0 + tc] = tile[tc][tr + i*8];
    __syncthreads();
  }
}

// ---------------- LayerNorm + RoPE -> bf16 hi/lo ----------------
__global__ __launch_bounds__(256) void ln_rope_kernel(
    const float* __restrict__ in, const float* __restrict__ sw, const float* __restrict__ bw,
    const float* __restrict__ cosT, const float* __restrict__ sinT,
    u16* __restrict__ outh, u16* __restrict__ outl) {
  __shared__ float xb[E_];
  __shared__ double red[256];
  __shared__ double stats[2];
  int t = blockIdx.x;
  int s = t / B_;
  const float* row = in + (size_t)t * E_;
  int tid = threadIdx.x;
  double sum = 0.0;
  for (int k = 0; k < 4; k++) {
    int e = tid + k*256;
    float f = row[e];
    xb[e] = f;
    sum += (double)f;
  }
  red[tid] = sum; __syncthreads();
  for (int off = 128; off > 0; off >>= 1) {
    if (tid < off) red[tid] += red[tid+off];
    __syncthreads();
  }
  if (tid == 0) stats[0] = red[0] / (double)E_;
  __syncthreads();
  double m = stats[0];
  double sq = 0.0;
  for (int k = 0; k < 4; k++) {
    int e = tid + k*256;
    double d = (double)xb[e] - m;
    sq += d*d;
  }
  red[tid] = sq; __syncthreads();
  for (int off = 128; off > 0; off >>= 1) {
    if (tid < off) red[tid] += red[tid+off];
    __syncthreads();
  }
  if (tid == 0) stats[1] = 1.0 / sqrt(red[0] / (double)E_ + 1e-5);
  __syncthreads();
  float mf = (float)m, rs = (float)stats[1];
  for (int k = 0; k < 2; k++) {
    int j = tid + k*256;    // 0..511
    float n1 = (xb[j]        - mf)*rs*sw[j]        + bw[j];
    float n2 = (xb[j+HALF_]  - mf)*rs*sw[j+HALF_]  + bw[j+HALF_];
    float c  = cosT[(size_t)s*HALF_ + j];
    float sn = sinT[(size_t)s*HALF_ + j];
    float o1 = n1*c - n2*sn;
    float o2 = n1*sn + n2*c;
    u16 h, l;
    splitf(o1, h, l);
    outh[(size_t)t*E_ + j] = h; outl[(size_t)t*E_ + j] = l;
    splitf(o2, h, l);
    outh[(size_t)t*E_ + HALF_ + j] = h; outl[(size_t)t*E_ + HALF_ + j] = l;
  }
}

// ---------------- LayerNorm (no rope) -> fp32 xn + bf16 xnb ----------------
__global__ __launch_bounds__(256) void ln2_kernel(
    const float* __restrict__ in, const float* __restrict__ sw, const float* __restrict__ bw,
    float* __restrict__ out, u16* __restrict__ outb) {
  __shared__ float xb[E_];
  __shared__ double red[256];
  __shared__ double stats[2];
  int t = blockIdx.x;
  const float* row = in + (size_t)t * E_;
  int tid = threadIdx.x;
  double sum = 0.0;
  for (int k = 0; k < 4; k++) {
    int e = tid + k*256;
    float f = row[e];
    xb[e] = f;
    sum += (double)f;
  }
  red[tid] = sum; __syncthreads();
  for (int off = 128; off > 0; off >>= 1) {
    if (tid < off) red[tid] += red[tid+off];
    __syncthreads();
  }
  if (tid == 0) stats[0] = red[0] / (double)E_;
  __syncthreads();
  double m = stats[0];
  double sq = 0.0;
  for (int k = 0; k < 4; k++) {
    int e = tid + k*256;
    double d = (double)xb[e] - m;
    sq += d*d;
  }
  red[tid] = sq; __syncthreads();
  for (int off = 128; off > 0; off >>= 1) {
    if (tid < off) red[tid] += red[tid+off];
    __syncthreads();
  }
  if (tid == 0) stats[1] = 1.0 / sqrt(red[0] / (double)E_ + 1e-5);
  __syncthreads();
  float mf = (float)m, rs = (float)stats[1];
  for (int k = 0; k < 4; k++) {
    int e = tid + k*256;
    float v = (xb[e] - mf)*rs*sw[e] + bw[e];
    out[(size_t)t*E_ + e] = v;
    outb[(size_t)t*E_ + e] = f2bf(v);
  }
}

// ---------------- MFMA GEMM: C = A[M][K] * B[N][K]^T ----------------
// MODE 0: split-3x, +bias, store bf16 hi/lo (QKV, z=0..2 selects slice)
// MODE 1: split-3x, +bias +res, store fp32 (out-proj)
template<int MODE>
__global__ __launch_bounds__(256) void gemm_mfma(
    const u16* __restrict__ Ah, const u16* __restrict__ Al,
    const u16* __restrict__ Bh, const u16* __restrict__ Bl,
    const float* __restrict__ bias, const float* __restrict__ res,
    float* __restrict__ Cf, u16* __restrict__ Ch, u16* __restrict__ Cl,
    int M, int N, int K) {
  __shared__ u16 Ash[128][40];
  __shared__ u16 Bsh[128][40];
  __shared__ u16 Asl[128][40];
  __shared__ u16 Bsl[128][40];
  int tid = threadIdx.x;
  int m0 = blockIdx.y*128, n0 = blockIdx.x*128;
  if constexpr (MODE == 0) {
    int z = blockIdx.z;
    Ah += (size_t)z*M*K;  Al += (size_t)z*M*K;
    Bh += (size_t)z*N*K;  Bl += (size_t)z*N*K;
    bias += (size_t)z*N;
    Ch += (size_t)z*M*N;  Cl += (size_t)z*M*N;
  }
  int wave = tid>>6, lane = tid&63, quad = lane>>4, l16 = lane&15;
  int wm = (wave>>1)*64, wn = (wave&1)*64;
  f32x4 acc[4][4];
  for (int i = 0; i < 4; i++)
    for (int j = 0; j < 4; j++)
      acc[i][j] = f32x4{0.f, 0.f, 0.f, 0.f};
  for (int k0 = 0; k0 < K; k0 += 32) {
    for (int c = tid; c < 512; c += 256) {
      int r = c >> 2, k8 = (c & 3) * 8;
      *(int4*)&Ash[r][k8] = *(const int4*)(Ah + (size_t)(m0+r)*K + k0 + k8);
      *(int4*)&Asl[r][k8] = *(const int4*)(Al + (size_t)(m0+r)*K + k0 + k8);
      *(int4*)&Bsh[r][k8] = *(const int4*)(Bh + (size_t)(n0+r)*K + k0 + k8);
      *(int4*)&Bsl[r][k8] = *(const int4*)(Bl + (size_t)(n0+r)*K + k0 + k8);
    }
    __syncthreads();
    bf16x8 af[4], bf[4];
    bf16x8 afl[4], bfl[4];
#pragma unroll
    for (int t4 = 0; t4 < 4; t4++) {
      af[t4] = *(const bf16x8*)&Ash[wm + t4*16 + l16][quad*8];
      bf[t4] = *(const bf16x8*)&Bsh[wn + t4*16 + l16][quad*8];
      afl[t4] = *(const bf16x8*)&Asl[wm + t4*16 + l16][quad*8];
      bfl[t4] = *(const bf16x8*)&Bsl[wn + t4*16 + l16][quad*8];
    }
#pragma unroll
    for (int i = 0; i < 4; i++)
#pragma unroll
      for (int j = 0; j < 4; j++) {
        f32x4 a = acc[i][j];
        a = mfma16(af[i],  bf[j],  a);
        a = mfma16(af[i],  bfl[j], a);
        a = mfma16(afl[i], bf[j],  a);
        acc[i][j] = a;
      }
    __syncthreads();
  }
  for (int i = 0; i < 4; i++) {
    for (int j = 0; j < 4; j++) {
      for (int r = 0; r < 4; r++) {
        int rl  = wm + i*16 + quad*4 + r;
        int col = n0 + wn + j*16 + l16;
        float v = acc[i][j][r];
        if constexpr (MODE == 0) {
          v += bias[col];
          u16 hi, lo; splitf(v, hi, lo);
          size_t o = (size_t)(m0+rl)*N + col;
          Ch[o] = hi; Cl[o] = lo;
        } else {
          size_t o = (size_t)(m0+rl)*N + col;
          Cf[o] = v + bias[col] + res[o];
        }
      }
    }
  }
}

// ---------------- gathered expert-FFN GEMM, 2-phase gl_lds pipeline ----------------
template<int MODE>
__global__ __launch_bounds__(256) void gemm_gather(
    const u16* __restrict__ A, const u16* __restrict__ B,
    const float* __restrict__ res,
    float* __restrict__ Cf, u16* __restrict__ Ch,
    int N, int K,
    const int* __restrict__ elist, const int* __restrict__ ecount) {
  __shared__ u16 As[2][128][32];
  __shared__ u16 Bs[2][128][32];
  __shared__ int toks[128];
  int tid = threadIdx.x;
  int m0 = blockIdx.y*128, n0 = blockIdx.x*128;
  int e = blockIdx.z;
  int cnt = ecount[e];
  if (m0 >= cnt) return;
  B += (size_t)e*N*K;
  const int* el = elist + e*CAP_;
  if (tid < 128) {
    int r = m0 + tid;
    toks[tid] = (r < cnt) ? el[r] : -1;
  }
  __syncthreads();
  int r0 = tid >> 2, ch0 = tid & 3;
  int r1 = r0 + 64;
  int s8 = (ch0 ^ (r0 & 3)) * 8;
  int tokA0 = toks[r0], tokA1 = toks[r1];
  const u16* gA0 = A + (size_t)(tokA0 >= 0 ? tokA0 : 0)*K + s8;
  const u16* gA1 = A + (size_t)(tokA1 >= 0 ? tokA1 : 0)*K + s8;
  const u16* gB0 = B + (size_t)(n0 + r0)*K + s8;
  const u16* gB1 = B + (size_t)(n0 + r1)*K + s8;
  u16* dA0 = &As[0][r0][ch0*8];
  u16* dA1 = &As[0][r1][ch0*8];
  u16* dB0 = &Bs[0][r0][ch0*8];
  u16* dB1 = &Bs[0][r1][ch0*8];
  int wave = tid>>6, lane = tid&63, quad = lane>>4, l16 = lane&15;
  int wm = (wave>>1)*64, wn = (wave&1)*64;
  int chA = (quad ^ (l16 & 3)) * 8;
  f32x4 acc[4][4];
  for (int i = 0; i < 4; i++)
    for (int j = 0; j < 4; j++)
      acc[i][j] = f32x4{0.f, 0.f, 0.f, 0.f};
  glds16(gA0, dA0); glds16(gA1, dA1);
  glds16(gB0, dB0); glds16(gB1, dB1);
  asm volatile("s_waitcnt vmcnt(0)" ::: "memory");
  __builtin_amdgcn_s_barrier();
  int cur = 0;
  for (int k0 = 0; k0 < K; k0 += 32) {
    int nxt = cur ^ 1;
    if (k0 + 32 < K) {
      int ko = k0 + 32;
      glds16(gA0 + ko, dA0 + nxt*4096); glds16(gA1 + ko, dA1 + nxt*4096);
      glds16(gB0 + ko, dB0 + nxt*4096); glds16(gB1 + ko, dB1 + nxt*4096);
    }
    const u16* aS = &As[cur][0][0];
    const u16* bS = &Bs[cur][0][0];
    bf16x8 af[4], bfr[4];
#pragma unroll
    for (int t4 = 0; t4 < 4; t4++) {
      af[t4]  = *(const bf16x8*)(aS + (wm + t4*16 + l16)*32 + chA);
      bfr[t4] = *(const bf16x8*)(bS + (wn + t4*16 + l16)*32 + chA);
    }
#pragma unroll
    for (int i = 0; i < 4; i++)
#pragma unroll
      for (int j = 0; j < 4; j++)
        acc[i][j] = mfma16(af[i], bfr[j], acc[i][j]);
    asm volatile("s_waitcnt vmcnt(0)" ::: "memory");
    __builtin_amdgcn_s_barrier();
    cur = nxt;
  }
  for (int i = 0; i < 4; i++) {
    for (int j = 0; j < 4; j++) {
      for (int r = 0; r < 4; r++) {
        int rl  = wm + i*16 + quad*4 + r;
        int col = n0 + wn + j*16 + l16;
        float v = acc[i][j][r];
        int tok = toks[rl];
        if (tok >= 0) {
          if constexpr (MODE == 2) {
            float g = 0.5f*v*(1.0f + erff(v*0.70710678118654752f));
            Ch[(size_t)tok*N + col] = f2bf(g);
          } else {
            size_t o = (size_t)tok*N + col;
            Cf[o] = v + res[o];
          }
        }
      }
    }
  }
}

// ---------------- flash attention, split-bf16 MFMA, TQ=64 / TK=64 ----------------
// V is pre-transposed globally ([bh][d=64][S]); pad=68 keeps all LDS ops <=2-way;
// next-tile global loads issued early (async-stage split) to hide latency.
__global__ __launch_bounds__(256) void attn_mfma_kernel(
    const u16* __restrict__ qh_, const u16* __restrict__ ql_,
    const u16* __restrict__ kh_, const u16* __restrict__ kl_,
    const u16* __restrict__ vth_, const u16* __restrict__ vtl_,
    u16* __restrict__ ch_, u16* __restrict__ cl_) {
  __shared__ u16 Kh[64][68], Kl[64][68];
  __shared__ u16 Vth[64][68], Vtl[64][68];   // [d][k], staged from global V^T
  __shared__ u16 Ph[64][68], Pl[64][68];     // [q][k]
  int bh = blockIdx.y;
  int b = bh >> 4, hh = bh & 15;
  int q0 = blockIdx.x * 64;
  int tid = threadIdx.x, wave = tid>>6, lane = tid&63, quad = lane>>4, l16 = lane&15;
  // Q fragments direct from global
  bf16x8 qfh[2], qfl[2];
  {
    int qrow = q0 + wave*16 + l16;
    size_t base = ((size_t)qrow*B_ + b)*E_ + hh*64;
    for (int st = 0; st < 2; st++) {
      qfh[st] = *(const bf16x8*)(qh_ + base + st*32 + quad*8);
      qfl[st] = *(const bf16x8*)(ql_ + base + st*32 + quad*8);
    }
  }
  // staging coords: entries c = tid and tid+256; r=c>>3 (row), k8=(c&7)*8
  int sr0 = tid >> 3, sk = (tid & 7) * 8;
  int sr1 = sr0 + 32;
  int4 rKh0, rKl0, rVh0, rVl0, rKh1, rKl1, rVh1, rVl1;
  auto issue = [&](int kt) {
    size_t gb0 = ((size_t)(kt*64 + sr0)*B_ + b)*E_ + hh*64 + sk;
    size_t gb1 = ((size_t)(kt*64 + sr1)*B_ + b)*E_ + hh*64 + sk;
    size_t gv0 = ((size_t)bh*64 + sr0)*S_ + kt*64 + sk;
    size_t gv1 = ((size_t)bh*64 + sr1)*S_ + kt*64 + sk;
    rKh0 = *(const int4*)(kh_ + gb0);  rKl0 = *(const int4*)(kl_ + gb0);
    rKh1 = *(const int4*)(kh_ + gb1);  rKl1 = *(const int4*)(kl_ + gb1);
    rVh0 = *(const int4*)(vth_ + gv0); rVl0 = *(const int4*)(vtl_ + gv0);
    rVh1 = *(const int4*)(vth_ + gv1); rVl1 = *(const int4*)(vtl_ + gv1);
  };
  float m_i[4], l_i[4];
  f32x4 acc[4];
  for (int r = 0; r < 4; r++) { m_i[r] = -INFINITY; l_i[r] = 0.f; }
  for (int d = 0; d < 4; d++) acc[d] = f32x4{0.f,0.f,0.f,0.f};
  issue(0);
  for (int kt = 0; kt < S_/64; kt++) {
    __syncthreads();           // prior iteration's LDS reads complete
    *(int4*)&Kh[sr0][sk] = rKh0;  *(int4*)&Kl[sr0][sk] = rKl0;
    *(int4*)&Kh[sr1][sk] = rKh1;  *(int4*)&Kl[sr1][sk] = rKl1;
    *(int4*)&Vth[sr0][sk] = rVh0; *(int4*)&Vtl[sr0][sk] = rVl0;
    *(int4*)&Vth[sr1][sk] = rVh1; *(int4*)&Vtl[sr1][sk] = rVl1;
    __syncthreads();           // stage visible
    if (kt + 1 < S_/64) issue(kt + 1);   // latency hides under compute
    // scores: wave's 16q x 64k band, 4 col-tiles
    f32x4 sc[4];
#pragma unroll
    for (int ct = 0; ct < 4; ct++) {
      f32x4 s = f32x4{0.f,0.f,0.f,0.f};
#pragma unroll
      for (int st = 0; st < 2; st++) {
        bf16x8 kh = *(const bf16x8*)&Kh[ct*16 + l16][st*32 + quad*8];
        bf16x8 kl = *(const bf16x8*)&Kl[ct*16 + l16][st*32 + quad*8];
        s = mfma16(qfh[st], kh, s);
        s = mfma16(qfh[st], kl, s);
        s = mfma16(qfl[st], kh, s);
      }
      sc[ct] = s;
    }
#pragma unroll
    for (int ct = 0; ct < 4; ct++)
#pragma unroll
      for (int r = 0; r < 4; r++)
        sc[ct][r] *= 0.125f;
    // online softmax
    float mx[4], alpha[4], rs[4];
#pragma unroll
    for (int r = 0; r < 4; r++)
      mx[r] = fmaxf(fmaxf(sc[0][r], sc[1][r]), fmaxf(sc[2][r], sc[3][r]));
#pragma unroll
    for (int off = 1; off < 16; off <<= 1)
#pragma unroll
      for (int r = 0; r < 4; r++)
        mx[r] = fmaxf(mx[r], __shfl_xor(mx[r], off, 64));
#pragma unroll
    for (int r = 0; r < 4; r++) {
      float mn = fmaxf(m_i[r], mx[r]);
      alpha[r] = expf(m_i[r] - mn);
      m_i[r] = mn;
      rs[r] = 0.f;
    }
#pragma unroll
    for (int ct = 0; ct < 4; ct++)
#pragma unroll
      for (int r = 0; r < 4; r++) {
        float p = expf(sc[ct][r] - m_i[r]);
        sc[ct][r] = p;
        rs[r] += p;
      }
#pragma unroll
    for (int off = 1; off < 16; off <<= 1)
#pragma unroll
      for (int r = 0; r < 4; r++)
        rs[r] += __shfl_xor(rs[r], off, 64);
#pragma unroll
    for (int r = 0; r < 4; r++)
      l_i[r] = l_i[r]*alpha[r] + rs[r];
    // write P (hi/lo) to LDS: wave-private rows (q = wave*16+..), read back by same wave
#pragma unroll
    for (int ct = 0; ct < 4; ct++)
#pragma unroll
      for (int r = 0; r < 4; r++) {
        u16 hi, lo; splitf(sc[ct][r], hi, lo);
        int q = wave*16 + quad*4 + r;
        int k = ct*16 + l16;
        Ph[q][k] = hi; Pl[q][k] = lo;
      }
#pragma unroll
    for (int d = 0; d < 4; d++)
#pragma unroll
      for (int r = 0; r < 4; r++)
        acc[d][r] *= alpha[r];
    // PV: intra-wave P round-trip (same-wave DS ordering) — no barrier needed
#pragma unroll
    for (int dt = 0; dt < 4; dt++) {
      f32x4 a = acc[dt];
#pragma unroll
      for (int st = 0; st < 2; st++) {
        bf16x8 ph = *(const bf16x8*)&Ph[wave*16 + l16][st*32 + quad*8];
        bf16x8 pl = *(const bf16x8*)&Pl[wave*16 + l16][st*32 + quad*8];
        bf16x8 vh = *(const bf16x8*)&Vth[dt*16 + l16][st*32 + quad*8];
        bf16x8 vl = *(const bf16x8*)&Vtl[dt*16 + l16][st*32 + quad*8];
        a = mfma16(ph, vh, a);
        a = mfma16(ph, vl, a);
        a = mfma16(pl, vh, a);
      }
      acc[dt] = a;
    }
  }
  // epilogue: ctx = acc / l, store hi/lo
  for (int dt = 0; dt < 4; dt++) {
    for (int r = 0; r < 4; r++) {
      float v = acc[dt][r] / l_i[r];
      int q = q0 + wave*16 + quad*4 + r;
      size_t o = ((size_t)q*B_ + b)*E_ + hh*64 + dt*16 + l16;
      u16 hi, lo; splitf(v, hi, lo);
      ch_[o] = hi; cl_[o] = lo;
    }
  }
}

// ---------------- router: logits (fp64 accum) + argmax ----------------
__global__ __launch_bounds__(256) void router_kernel(
    const float* __restrict__ xn, const float* __restrict__ rw, int* __restrict__ top) {
  __shared__ float lg[32][9];
  int t0 = blockIdx.x * 32;
  int tl = threadIdx.x >> 3;
  int n = threadIdx.x & 7;
  int t = t0 + tl;
  const float* xr = xn + (size_t)t * E_;
  double acc = 0.0;
  for (int e = 0; e < E_; e++) acc += (double)xr[e] * (double)rw[e*NE_ + n];
  lg[tl][n] = (float)acc;
  __syncthreads();
  if (n == 0) {
    float best = lg[tl][0]; int bi = 0;
    for (int i = 1; i < 8; i++) {
      float v = lg[tl][i];
      if (v > best) { best = v; bi = i; }
    }
    top[t] = bi;
  }
}

// ---------------- capacity (Switch cumsum) ----------------
__global__ __launch_bounds__(256) void capacity_kernel(
    const int* __restrict__ top, int* __restrict__ elist, int* __restrict__ ecount) {
  __shared__ int tl[T_];
  __shared__ int cnts[256][NE_];
  int tid = threadIdx.x;
  for (int i = tid; i < T_; i += 256) tl[i] = top[i];
  __syncthreads();
  int c[NE_] = {};
  int base = tid * 32;
  for (int i = 0; i < 32; i++) c[tl[base+i]]++;
  for (int n = 0; n < NE_; n++) cnts[tid][n] = c[n];
  __syncthreads();
  if (tid < NE_) {
    int run = 0;
    for (int i = 0; i < 256; i++) {
      int v = cnts[i][tid];
      cnts[i][tid] = run;
      run += v;
    }
    ecount[tid] = min(run, CAP_);
  }
  __syncthreads();
  int pos[NE_];
  for (int n = 0; n < NE_; n++) pos[n] = cnts[tid][n];
  for (int i = 0; i < 32; i++) {
    int t = base + i;
    int e = tl[t];
    int p = pos[e]++;
    if (p < CAP_) elist[e*CAP_ + p] = t;
  }
}

// ---------------- out = x (dropped tokens keep residual) ----------------
__global__ __launch_bounds__(256) void fill_out_kernel(
    const float* __restrict__ x, float* __restrict__ out) {
  size_t i4 = ((size_t)blockIdx.x*256 + threadIdx.x) * 4;
  *(float4*)(out + i4) = *(const float4*)(x + i4);
}

extern "C" void kernel_launch(void* const* d_in, const int* in_sizes, int n_in,
                              void* d_out, int out_size, void* d_ws, size_t ws_size,
                              hipStream_t stream) {
  (void)in_sizes; (void)n_in; (void)out_size; (void)ws_size;
  const float* query      = (const float*)d_in[0];
  const float* key        = (const float*)d_in[1];
  const float* value      = (const float*)d_in[2];
  const float* in_proj_w  = (const float*)d_in[3];
  const float* in_proj_b  = (const float*)d_in[4];
  const float* out_proj_w = (const float*)d_in[5];
  const float* out_proj_b = (const float*)d_in[6];
  const float* norm1_s    = (const float*)d_in[7];
  const float* norm1_b    = (const float*)d_in[8];
  const float* norm2_s    = (const float*)d_in[9];
  const float* norm2_b    = (const float*)d_in[10];
  const float* router_w   = (const float*)d_in[11];
  const float* wi         = (const float*)d_in[12];
  const float* wo         = (const float*)d_in[13];
  float* out = (float*)d_out;

  char* wsb = (char*)d_ws;
  const size_t TE = (size_t)T_ * E_;          // 8,388,608
  // R1 @0 (134,217,728 B): LN outputs hi/lo [3][T][E]; later wit+wot
  u16* nh  = (u16*)(wsb + 0);                 // 3*TE shorts
  u16* nl  = nh + 3*TE;
  u16* wit = (u16*)(wsb + 0);                 // [8][F][E] bf16
  u16* wot = wit + (size_t)8*F_*E_;
  // R2 @134,217,728 (100,663,296 B): QKV proj hi/lo [3][T][E]; later h + xnb
  u16* pph  = (u16*)(wsb + 134217728ULL);
  u16* ppl  = pph + 3*TE;
  u16* hbuf = (u16*)(wsb + 134217728ULL);     // [T][F] bf16
  u16* xnb  = hbuf + (size_t)T_*F_;
  // R3 @234,881,024 (33,554,432 B): ctx hi/lo; later xn fp32
  u16* ctxh = (u16*)(wsb + 234881024ULL);
  u16* ctxl = ctxh + TE;
  float* xn = (float*)(wsb + 234881024ULL);
  // R4 @268,435,456 (33,554,432 B): V^T hi/lo during attn; later x fp32
  u16* vth = (u16*)(wsb + 268435456ULL);
  u16* vtl = vth + TE;
  float* x  = (float*)(wsb + 268435456ULL);
  // R5: trig
  float* cosT = (float*)(wsb + 301989888ULL);
  float* sinT = cosT + (size_t)S_*HALF_;
  // R6: proj weight splits
  u16* iph = (u16*)(wsb + 310378496ULL);
  u16* ipl = iph + (size_t)3*E_*E_;
  u16* oph = ipl + (size_t)3*E_*E_;
  u16* opl = oph + (size_t)E_*E_;
  // R7: routing
  int* top    = (int*)(wsb + 327155712ULL);
  int* elist  = top + T_;
  int* ecount = elist + NE_*CAP_;

  trig_kernel<<<dim3(S_), dim3(256), 0, stream>>>(cosT, sinT);
  split_kernel<<<dim3((3*E_*E_)/256), dim3(256), 0, stream>>>(in_proj_w, iph, ipl, 3*E_*E_);
  split_kernel<<<dim3((E_*E_)/256), dim3(256), 0, stream>>>(out_proj_w, oph, opl, E_*E_);
  ln_rope_kernel<<<dim3(T_), dim3(256), 0, stream>>>(query, norm1_s, norm1_b, cosT, sinT, nh,        nl);
  ln_rope_kernel<<<dim3(T_), dim3(256), 0, stream>>>(key,   norm1_s, norm1_b, cosT, sinT, nh + TE,   nl + TE);
  ln_rope_kernel<<<dim3(T_), dim3(256), 0, stream>>>(value, norm1_s, norm1_b, cosT, sinT, nh + 2*TE, nl + 2*TE);
  // QKV projections (split-3x)
  gemm_mfma<0><<<dim3(E_/128, T_/128, 3), dim3(256), 0, stream>>>(
      nh, nl, iph, ipl, in_proj_b, nullptr, nullptr, pph, ppl,
      T_, E_, E_);
  // V pre-transpose into R4 (x not live yet)
  vtransp_kernel<<<dim3(S_/32, 2, B_*H_), dim3(256), 0, stream>>>(
      pph + 2*TE, ppl + 2*TE, vth, vtl);
  // wi/wo transpose+convert (R1 now free)
  transp_bf16_kernel<<<dim3(F_/32, E_/32, 8), dim3(256), 0, stream>>>(wi, wit, E_, F_);
  transp_bf16_kernel<<<dim3(E_/32, F_/32, 8), dim3(256), 0, stream>>>(wo, wot, F_, E_);
  attn_mfma_kernel<<<dim3(S_/64, B_*H_), dim3(256), 0, stream>>>(
      pph, ppl, pph + TE, ppl + TE, vth, vtl, ctxh, ctxl);
  // out-proj (split-3x) + bias + residual(query) -> x fp32 (V^T dead now)
  gemm_mfma<1><<<dim3(E_/128, T_/128, 1), dim3(256), 0, stream>>>(
      ctxh, ctxl, oph, opl, out_proj_b, query, x, nullptr, nullptr,
      T_, E_, E_);
  ln2_kernel<<<dim3(T_), dim3(256), 0, stream>>>(x, norm2_s, norm2_b, xn, xnb);
  router_kernel<<<dim3(T_/32), dim3(256), 0, stream>>>(xn, router_w, top);
  capacity_kernel<<<dim3(1), dim3(256), 0, stream>>>(top, elist, ecount);
  fill_out_kernel<<<dim3(TE/1024), dim3(256), 0, stream>>>(x, out);
  // expert FFN (plain bf16 MFMA, gathered, 2-phase gl_lds pipeline)
  gemm_gather<2><<<dim3(F_/128, CAP_/128, NE_), dim3(256), 0, stream>>>(
      xnb, wit, nullptr, nullptr, hbuf, F_, E_, elist, ecount);
  gemm_gather<3><<<dim3(E_/128, CAP_/128, NE_), dim3(256), 0, stream>>>(
      hbuf, wot, x, out, nullptr, E_, F_, elist, ecount);
}